// Round 5
// baseline (1121.406 us; speedup 1.0000x reference)
//
#include <hip/hip_runtime.h>
#include <hip/hip_bf16.h>
#include <math.h>

#define TT 512   // T
#define BB 128   // B
#define EE 100   // embed dim
#define HH 128   // hidden
#define G4 512   // 4*H
#define K1 256   // 2*H

typedef __attribute__((ext_vector_type(8))) short bf16x8;
typedef __attribute__((ext_vector_type(4))) float f32x4;
typedef __attribute__((ext_vector_type(2))) float f32x2;

__device__ inline void split2(float v, unsigned short& hi, unsigned short& lo) {
    __hip_bfloat16 h = __float2bfloat16(v);
    float hf = __bfloat162float(h);
    __hip_bfloat16 l = __float2bfloat16(v - hf);
    hi = *reinterpret_cast<unsigned short*>(&h);
    lo = *reinterpret_cast<unsigned short*>(&l);
}

__device__ inline void gload16(const void* g, void* l) {
    __builtin_amdgcn_global_load_lds(
        (const __attribute__((address_space(1))) void*)g,
        (__attribute__((address_space(3))) void*)l, 16, 0, 0);
}

// ---- embedding -> xs2 bf16 [hi(128) | lo(128)] per (t,b) row ---------------
__global__ void embed_cvt(const int* __restrict__ x, const float* __restrict__ emb,
                          unsigned short* __restrict__ xs2) {
    int row = blockIdx.x;          // t*B + b
    int k = threadIdx.x;           // 0..127
    int b = row & 127, t = row >> 7;
    int tok = x[b * TT + t];
    float v = (k < EE) ? emb[(size_t)tok * EE + k] : 0.f;
    unsigned short hi, lo;
    split2(v, hi, lo);
    xs2[(size_t)row * 256 + k] = hi;
    xs2[(size_t)row * 256 + 128 + k] = lo;
}

// ---- weight -> bf16 [hi(Kp)|lo(Kp)], rows PERMUTED to unit-major ----------
// dst row n' <- src row ((n'&3)<<7)|(n'>>2)  (so C col n' = gate n'&3 of unit n'>>2)
__global__ void wcvt(const float* __restrict__ src, int Kin, int Kp,
                     unsigned short* __restrict__ dst) {
    int n = blockIdx.x;            // 0..511 (dst row)
    int k = threadIdx.x;           // 0..Kp-1
    int r = ((n & 3) << 7) | (n >> 2);
    float v = (k < Kin) ? src[(size_t)r * Kin + k] : 0.f;
    unsigned short hi, lo;
    split2(v, hi, lo);
    dst[(size_t)n * 2 * Kp + k] = hi;
    dst[(size_t)n * 2 * Kp + Kp + k] = lo;
}

// ---- bias: dst[dir*512+n] = bih[perm(n)] + bhh[perm(n)] -------------------
__global__ void bias_cat(const float* __restrict__ bihf, const float* __restrict__ bhhf,
                         const float* __restrict__ bihr, const float* __restrict__ bhhr,
                         float* __restrict__ dst) {
    int n = blockIdx.x * 256 + threadIdx.x;   // 0..1023
    int d = n >> 9, m = n & 511;
    int src = ((m & 3) << 7) | (m >> 2);
    const float* a = d ? bihr : bihf;
    const float* c = d ? bhhr : bhhf;
    dst[n] = a[src] + c[src];
}

// ---- merged MFMA GEMM (fwd+bwd): grid (8, TC) -----------------------------
// blockIdx.x: dir = bx>>2, n-tile = bx&3. W2cat = fwd 512 rows then bwd 512.
template<int K2>
__global__ __launch_bounds__(256) void gemm_mfma(
    const unsigned short* __restrict__ A2,
    const unsigned short* __restrict__ W2cat,
    const float* __restrict__ biascat,     // (1024,) permuted, bih+bhh
    float* __restrict__ Cf, float* __restrict__ Cr,
    int t_base)
{
    __shared__ bf16x8 As[1024];   // 128 rows x 128 B (64 bf16), swizzled
    __shared__ bf16x8 Bs[1024];
    int tid = threadIdx.x;
    int s = blockIdx.y;
    int dir = blockIdx.x >> 2;
    int nBase = (blockIdx.x & 3) * 128;
    int t = dir ? (TT - 1 - t_base - s) : (t_base + s);
    float* C = dir ? Cr : Cf;
    const unsigned short* Abase = A2 + (size_t)t * BB * K2;
    const unsigned short* Wbase = W2cat + (size_t)(dir * 512 + nBase) * K2;
    int lane = tid & 63, wid = tid >> 6;
    int wr = wid >> 1, wc = wid & 1;
    int l15 = lane & 15, g = lane >> 4;

    f32x4 acc[4][4];
    const f32x4 z = {0.f, 0.f, 0.f, 0.f};
    #pragma unroll
    for (int i = 0; i < 4; ++i)
        #pragma unroll
        for (int j = 0; j < 4; ++j) acc[i][j] = z;

    for (int kt = 0; kt < K2 / 64; ++kt) {
        #pragma unroll
        for (int j = 0; j < 4; ++j) {
            int p = tid + j * 256;
            int row = p >> 3;
            int k16 = (p & 7) ^ (row & 7);   // pre-swizzled source chunk
            size_t goff = (size_t)row * K2 + kt * 64 + k16 * 8;
            gload16(Abase + goff, &As[p]);
            gload16(Wbase + goff, &Bs[p]);
        }
        __syncthreads();
        #pragma unroll
        for (int ks = 0; ks < 2; ++ks) {
            bf16x8 af[4], bfr[4];
            #pragma unroll
            for (int i = 0; i < 4; ++i) {
                int arow = wr * 64 + i * 16 + l15;
                int abyte = arow * 128 + ((ks * 64 + g * 16) ^ ((arow & 7) << 4));
                af[i] = As[abyte >> 4];
                int brow = wc * 64 + i * 16 + l15;
                int bbyte = brow * 128 + ((ks * 64 + g * 16) ^ ((brow & 7) << 4));
                bfr[i] = Bs[bbyte >> 4];
            }
            #pragma unroll
            for (int i = 0; i < 4; ++i)
                #pragma unroll
                for (int j = 0; j < 4; ++j)
                    acc[i][j] = __builtin_amdgcn_mfma_f32_16x16x32_bf16(
                        af[i], bfr[j], acc[i][j], 0, 0, 0);
        }
        __syncthreads();
    }
    #pragma unroll
    for (int i = 0; i < 4; ++i) {
        size_t crow0 = (size_t)s * 128 + wr * 64 + i * 16 + g * 4;
        #pragma unroll
        for (int j = 0; j < 4; ++j) {
            int col = nBase + wc * 64 + j * 16 + l15;
            float bsum = biascat[dir * 512 + col];
            #pragma unroll
            for (int r = 0; r < 4; ++r)
                C[(crow0 + r) * G4 + col] = acc[i][j][r] + bsum;
        }
    }
}

__device__ inline float sig_fast(float z) {
    return __builtin_amdgcn_rcpf(1.f + __expf(-z));
}

// ---- LSTM recurrence: one block per (dir, b); 512 thr; quad-per-unit ------
// thread (u = tid>>2, q = tid&3): K-slice [32q,32q+32) of all 4 gate rows of
// unit u (w resident in 128 VGPRs). Butterfly gives every lane all 4 gate
// sums; gin is one float4 (unit-major gx layout); all lanes compute i,f,g,o.
__global__ __launch_bounds__(512, 1) void lstm_chunk(
    const float* __restrict__ gxf,        // (TC*B, 512) unit-major, fwd order
    const float* __restrict__ gxr,        // (TC*B, 512) unit-major, bwd order
    const float* __restrict__ whhf,
    const float* __restrict__ whhr,
    float* __restrict__ h_state,          // (2, B, 128)
    float* __restrict__ c_state,          // (2, B, 128)
    unsigned short* __restrict__ out_x1,  // x1_2 (T*B,512) bf16 [hi|lo], or null
    int t_base, int TC)
{
    int blk = blockIdx.x;
    int dir = blk >> 7;
    int b   = blk & 127;
    const float* gx  = dir ? gxr : gxf;
    const float* whh = dir ? whhr : whhf;
    int tid = threadIdx.x;
    int u = tid >> 2, q = tid & 3;

    // pack w rows {g*128+u}, K-slice [32q,32q+32) as f32x2 pairs (g0,g1),(g2,g3)
    f32x2 wp01[32], wp23[32];
    {
        const float* w0 = whh + ((size_t)(0 * 128 + u)) * 128 + q * 32;
        const float* w1 = whh + ((size_t)(1 * 128 + u)) * 128 + q * 32;
        const float* w2 = whh + ((size_t)(2 * 128 + u)) * 128 + q * 32;
        const float* w3 = whh + ((size_t)(3 * 128 + u)) * 128 + q * 32;
        #pragma unroll
        for (int kb = 0; kb < 8; ++kb) {
            float4 a = *reinterpret_cast<const float4*>(w0 + kb * 4);
            float4 bv = *reinterpret_cast<const float4*>(w1 + kb * 4);
            float4 cv = *reinterpret_cast<const float4*>(w2 + kb * 4);
            float4 dv = *reinterpret_cast<const float4*>(w3 + kb * 4);
            wp01[kb*4+0] = f32x2{a.x, bv.x}; wp23[kb*4+0] = f32x2{cv.x, dv.x};
            wp01[kb*4+1] = f32x2{a.y, bv.y}; wp23[kb*4+1] = f32x2{cv.y, dv.y};
            wp01[kb*4+2] = f32x2{a.z, bv.z}; wp23[kb*4+2] = f32x2{cv.z, dv.z};
            wp01[kb*4+3] = f32x2{a.w, bv.w}; wp23[kb*4+3] = f32x2{cv.w, dv.w};
        }
    }

    // ping-pong h buffer: quarter q at float offset 40q (bank-shifted, 16B-aligned)
    __shared__ float hb[2][160];
    int sbase = (dir * BB + b) * HH;
    int hslot = (u >> 5) * 40 + (u & 31);
    float c = c_state[sbase + u];
    float h = 0.f;
    if (q == 0) hb[0][hslot] = h_state[sbase + u];
    __syncthreads();

    float4 gin4 = *reinterpret_cast<const float4*>(gx + ((size_t)0 * BB + b) * G4 + 4 * u);

    for (int s = 0; s < TC; ++s) {
        int p = s & 1;
        int sn = (s + 1 < TC) ? s + 1 : s;
        float4 gin4n = *reinterpret_cast<const float4*>(
            gx + ((size_t)sn * BB + b) * G4 + 4 * u);

        // dot over this thread's K-slice: 4 independent chains per gate-pair
        f32x2 s01[4], s23[4];
        #pragma unroll
        for (int e = 0; e < 4; ++e) { s01[e] = f32x2{0.f, 0.f}; s23[e] = f32x2{0.f, 0.f}; }
        const float4* hb4 = reinterpret_cast<const float4*>(&hb[p][40 * q]);
        #pragma unroll
        for (int kb = 0; kb < 8; ++kb) {
            float4 hv = hb4[kb];
            f32x2 h0 = {hv.x, hv.x}, h1 = {hv.y, hv.y};
            f32x2 h2 = {hv.z, hv.z}, h3 = {hv.w, hv.w};
            s01[0] = __builtin_elementwise_fma(wp01[kb*4+0], h0, s01[0]);
            s23[0] = __builtin_elementwise_fma(wp23[kb*4+0], h0, s23[0]);
            s01[1] = __builtin_elementwise_fma(wp01[kb*4+1], h1, s01[1]);
            s23[1] = __builtin_elementwise_fma(wp23[kb*4+1], h1, s23[1]);
            s01[2] = __builtin_elementwise_fma(wp01[kb*4+2], h2, s01[2]);
            s23[2] = __builtin_elementwise_fma(wp23[kb*4+2], h2, s23[2]);
            s01[3] = __builtin_elementwise_fma(wp01[kb*4+3], h3, s01[3]);
            s23[3] = __builtin_elementwise_fma(wp23[kb*4+3], h3, s23[3]);
        }
        f32x2 acc01 = (s01[0] + s01[1]) + (s01[2] + s01[3]);
        f32x2 acc23 = (s23[0] + s23[1]) + (s23[2] + s23[3]);

        // quad butterfly: all 4 lanes get full sums for all 4 gates
        f32x2 t;
        t.x = __shfl_xor(acc01.x, 1); t.y = __shfl_xor(acc01.y, 1); acc01 += t;
        t.x = __shfl_xor(acc23.x, 1); t.y = __shfl_xor(acc23.y, 1); acc23 += t;
        t.x = __shfl_xor(acc01.x, 2); t.y = __shfl_xor(acc01.y, 2); acc01 += t;
        t.x = __shfl_xor(acc23.x, 2); t.y = __shfl_xor(acc23.y, 2); acc23 += t;

        float pi = acc01.x + gin4.x;
        float pf = acc01.y + gin4.y;
        float pg = acc23.x + gin4.z;
        float po = acc23.y + gin4.w;
        float ig = sig_fast(pi);
        float fg = sig_fast(pf);
        float og = sig_fast(po);
        float gg = __builtin_fmaf(2.f, sig_fast(2.f * pg), -1.f);

        c = fg * c + ig * gg;
        float th = __builtin_fmaf(2.f, sig_fast(2.f * c), -1.f);
        h = og * th;

        if (q == 0) hb[p ^ 1][hslot] = h;
        if (out_x1 && q < 2) {
            int tg = dir ? (TT - 1 - (t_base + s)) : (t_base + s);
            size_t base = ((size_t)tg * BB + b) * 512;
            unsigned short hi, lo;
            split2(h, hi, lo);
            if (q == 0) out_x1[base + dir * HH + u] = hi;
            else        out_x1[base + 256 + dir * HH + u] = lo;
        }
        asm volatile("s_waitcnt lgkmcnt(0)" ::: "memory");
        __builtin_amdgcn_s_barrier();
        asm volatile("" ::: "memory");
        gin4 = gin4n;
    }
    if (q == 0) {
        h_state[sbase + u] = h;
        c_state[sbase + u] = c;
    }
}

// ---- FC head --------------------------------------------------------------
__global__ void fc_kernel(const float* __restrict__ h_state,  // (2,B,128)
                          const float* __restrict__ fc_w,     // (3,256)
                          const float* __restrict__ fc_b,     // (3,)
                          float* __restrict__ out) {          // (B,3)
    int tid = blockIdx.x * blockDim.x + threadIdx.x;
    if (tid >= BB * 3) return;
    int b = tid / 3;
    int c = tid % 3;
    float acc = 0.f;
    for (int j = 0; j < 256; ++j) {
        float v = (j < HH) ? h_state[((size_t)0 * BB + b) * HH + j]
                           : h_state[((size_t)1 * BB + b) * HH + (j - HH)];
        acc += v * fc_w[c * 256 + j];
    }
    out[b * 3 + c] = acc + fc_b[c];
}

extern "C" void kernel_launch(void* const* d_in, const int* in_sizes, int n_in,
                              void* d_out, int out_size, void* d_ws, size_t ws_size,
                              hipStream_t stream) {
    const int*   x        = (const int*)  d_in[0];
    const float* emb      = (const float*)d_in[1];
    const float* w_ih_l0  = (const float*)d_in[2];
    const float* w_hh_l0  = (const float*)d_in[3];
    const float* b_ih_l0  = (const float*)d_in[4];
    const float* b_hh_l0  = (const float*)d_in[5];
    const float* w_ih_l0r = (const float*)d_in[6];
    const float* w_hh_l0r = (const float*)d_in[7];
    const float* b_ih_l0r = (const float*)d_in[8];
    const float* b_hh_l0r = (const float*)d_in[9];
    const float* w_ih_l1  = (const float*)d_in[10];
    const float* w_hh_l1  = (const float*)d_in[11];
    const float* b_ih_l1  = (const float*)d_in[12];
    const float* b_hh_l1  = (const float*)d_in[13];
    const float* w_ih_l1r = (const float*)d_in[14];
    const float* w_hh_l1r = (const float*)d_in[15];
    const float* b_ih_l1r = (const float*)d_in[16];
    const float* b_hh_l1r = (const float*)d_in[17];
    const float* fc_w     = (const float*)d_in[18];
    const float* fc_b     = (const float*)d_in[19];
    float* out = (float*)d_out;
    (void)in_sizes; (void)n_in; (void)out_size;

    // ---- workspace layout ----
    size_t xs2_b   = (size_t)TT * BB * 256 * 2;         // 33.6 MB
    size_t x1_b    = (size_t)TT * BB * 512 * 2;         // 67.1 MB (bf16 hi|lo)
    size_t w2l0_b  = (size_t)512 * 256 * 2;             // 256 KB
    size_t w2l1_b  = (size_t)512 * 512 * 2;             // 512 KB
    size_t bias_b  = (size_t)1024 * 4;                  // 4 KB
    size_t state_b = (size_t)2 * BB * HH * 4;           // 128 KB
    size_t fixed = xs2_b + x1_b + 2 * w2l0_b + 2 * w2l1_b + 2 * bias_b
                 + 2 * state_b + 4096;
    int TC = 512;
    while (TC > 8) {
        size_t chunk2 = (size_t)TC * BB * G4 * 4 * 2;
        if (fixed + chunk2 <= ws_size) break;
        TC >>= 1;
    }
    char* ws = (char*)d_ws;
    size_t off = 0;
    unsigned short* xs2   = (unsigned short*)(ws + off); off += xs2_b;
    unsigned short* x1_2  = (unsigned short*)(ws + off); off += x1_b;
    unsigned short* w2l0f = (unsigned short*)(ws + off); off += w2l0_b;   // cat: fwd..
    unsigned short* w2l0r = (unsigned short*)(ws + off); off += w2l0_b;   // ..bwd
    unsigned short* w2l1f = (unsigned short*)(ws + off); off += w2l1_b;
    unsigned short* w2l1r = (unsigned short*)(ws + off); off += w2l1_b;
    float* biasl0  = (float*)(ws + off); off += bias_b;
    float* biasl1  = (float*)(ws + off); off += bias_b;
    float* h_state = (float*)(ws + off); off += state_b;
    float* c_state = (float*)(ws + off); off += state_b;
    float* gxf     = (float*)(ws + off); off += (size_t)TC * BB * G4 * 4;
    float* gxr     = (float*)(ws + off);

    int NC = TT / TC;
    dim3 ggrid(8, TC);

    // ---- precompute bf16 hi|lo forms (rows permuted to unit-major) ----
    embed_cvt<<<TT * BB, 128, 0, stream>>>(x, emb, xs2);
    wcvt<<<512, 128, 0, stream>>>(w_ih_l0,  EE, 128, w2l0f);
    wcvt<<<512, 128, 0, stream>>>(w_ih_l0r, EE, 128, w2l0r);
    wcvt<<<512, 256, 0, stream>>>(w_ih_l1,  K1, 256, w2l1f);
    wcvt<<<512, 256, 0, stream>>>(w_ih_l1r, K1, 256, w2l1r);
    bias_cat<<<4, 256, 0, stream>>>(b_ih_l0, b_hh_l0, b_ih_l0r, b_hh_l0r, biasl0);
    bias_cat<<<4, 256, 0, stream>>>(b_ih_l1, b_hh_l1, b_ih_l1r, b_hh_l1r, biasl1);

    // ---- layer 0 ----
    hipMemsetAsync(h_state, 0, state_b, stream);
    hipMemsetAsync(c_state, 0, state_b, stream);
    for (int ci = 0; ci < NC; ++ci) {
        int t0 = ci * TC;
        gemm_mfma<256><<<ggrid, 256, 0, stream>>>(xs2, w2l0f, biasl0, gxf, gxr, t0);
        lstm_chunk<<<256, 512, 0, stream>>>(gxf, gxr, w_hh_l0, w_hh_l0r,
                                            h_state, c_state, x1_2, t0, TC);
    }
    // ---- layer 1 ----
    hipMemsetAsync(h_state, 0, state_b, stream);
    hipMemsetAsync(c_state, 0, state_b, stream);
    for (int ci = 0; ci < NC; ++ci) {
        int t0 = ci * TC;
        gemm_mfma<512><<<ggrid, 256, 0, stream>>>(x1_2, w2l1f, biasl1, gxf, gxr, t0);
        lstm_chunk<<<256, 512, 0, stream>>>(gxf, gxr, w_hh_l1, w_hh_l1r,
                                            h_state, c_state, nullptr, t0, TC);
    }
    // ---- FC head ----
    fc_kernel<<<2, 192, 0, stream>>>(h_state, fc_w, fc_b, out);
}